// Round 1
// baseline (26972.180 us; speedup 1.0000x reference)
//
#include <hip/hip_runtime.h>

typedef _Float16 f16;
typedef _Float16 f16x8 __attribute__((ext_vector_type(8)));
typedef float f32x16 __attribute__((ext_vector_type(16)));

#define HID   512
#define BT    64
#define NSTEP 100
#define WMAT  786432   // halfs per packed weight matrix (1536*512)

__device__ __forceinline__ float sigmoid_f(float x) {
  return 1.0f / (1.0f + __expf(-x));
}
__device__ __forceinline__ float tanh_f(float x) {
  float e = __expf(2.0f * x);
  return 1.0f - 2.0f / (e + 1.0f);
}
__device__ __forceinline__ f32x16 mfma16(f16x8 a, f16x8 b, f32x16 c) {
  return __builtin_amdgcn_mfma_f32_32x32x16_f16(a, b, c, 0, 0, 0);
}

// ---- weight pack: fp32 [1536][512] row-major -> B-fragment-packed fp16 ----
// layout [ct(48)][kt(32)][lane(64)][i(8)]:
//   gate = ct*32 + (lane&31), k = kt*16 + (lane>>5)*8 + i
// (exact v_mfma_f32_32x32x16_f16 B layout: col=lane&31, k = 8*(lane>>5)+i)
__global__ void pack_weights(const float* __restrict__ W, f16* __restrict__ out) {
  int t = blockIdx.x * 256 + threadIdx.x;
  if (t >= 48 * 32 * 64) return;
  int lane = t & 63;
  int kt   = (t >> 6) & 31;
  int ct   = t >> 11;
  int gate = ct * 32 + (lane & 31);
  int k0   = kt * 16 + (lane >> 5) * 8;
  const float* src = W + gate * HID + k0;
  f16x8 v;
#pragma unroll
  for (int i = 0; i < 8; ++i) v[i] = (f16)src[i];
  *(f16x8*)(out + (size_t)t * 8) = v;
}

// combined biases: out[0..1023] = bi+bh (r,z gates), [1024..1535]=bi_n, [1536..2047]=bh_n
__global__ void pack_bias(const float* __restrict__ bi, const float* __restrict__ bh,
                          float* __restrict__ out) {
  int j = blockIdx.x * 256 + threadIdx.x;
  if (j < 1024)      out[j] = bi[j] + bh[j];
  else if (j < 1536) out[j] = bi[j];
  else if (j < 2048) out[j] = bh[j - 512];
}

// Persistent per-block GRU: block = 64 batch rows, 8 waves, 99 steps.
// h element (row,k) lives at LDS byte: row*1024 + ((2k) ^ ((row&7)<<4))
__global__ __launch_bounds__(512) void gru_fused(
    const float* __restrict__ z,
    const float* __restrict__ w_ih1,   // [1536][3] fp32
    const float* __restrict__ fc_w,    // [3][512]  fp32
    const float* __restrict__ fc_b,    // [3]
    const f16*  __restrict__ Wp,       // packed Whh1 | Wih2 | Whh2
    const float* __restrict__ Bb,      // bias1[2048] | bias2[2048]
    float* __restrict__ out)           // [B][100][3] fp32
{
  __shared__ f16  h1s[BT * HID];
  __shared__ f16  h2s[BT * HID];
  __shared__ float xs[BT * 4];

  const int tid  = threadIdx.x;
  const int lane = tid & 63;
  const int wv   = tid >> 6;
  const int b0   = blockIdx.x * BT;

  {
    f16x8 z8 = {0, 0, 0, 0, 0, 0, 0, 0};
    for (int i = tid; i < BT * HID / 8; i += 512) {
      ((f16x8*)h1s)[i] = z8;
      ((f16x8*)h2s)[i] = z8;
    }
  }
  if (tid < BT * 3) {
    int rr = tid / 3, oo = tid - rr * 3;
    float v = z[(size_t)(b0 + rr) * 6 + 3 + oo];
    xs[rr * 4 + oo] = v;
    out[(size_t)(b0 + rr) * 300 + oo] = v;   // t = 0 output
  }
  __syncthreads();

  const int colid = lane & 31;         // A row offset / D col offset / B col offset
  const int khalf = lane >> 5;         // k half-block select
  const int klo   = khalf << 4;        // byte offset inside 32-byte k-tile
  const int patA  = (colid & 7) << 4;  // XOR bank swizzle (rows rt*32+colid share it)
  const int rbase0 = colid * 1024;
  const int rbase1 = (32 + colid) * 1024;
  const int jw = wv << 6;              // this wave owns hidden cols [jw, jw+64)

  const f16* W1  = Wp;
  const f16* Wi2 = Wp + WMAT;
  const f16* Wh2 = Wp + 2 * WMAT;
  const float* B1 = Bb;
  const float* B2 = Bb + 2048;

  for (int t = 1; t < NSTEP; ++t) {
    f16 hnew[64];   // deferred h-writes: [chunk(2)][rt(2)][reg(16)]

    // ================= GRU layer 1: gh1 = h1 @ Whh1^T =================
#pragma unroll
    for (int c = 0; c < 2; ++c) {
      const int jb = jw + (c << 5);
      f32x16 aR[2], aZ[2], aN[2];
#pragma unroll
      for (int q = 0; q < 16; ++q) {
        aR[0][q]=0.f; aR[1][q]=0.f; aZ[0][q]=0.f; aZ[1][q]=0.f; aN[0][q]=0.f; aN[1][q]=0.f;
      }
      const f16* Br = W1 + (size_t)((jb)        >> 5) * 16384 + lane * 8;
      const f16* Bz = W1 + (size_t)((512 + jb)  >> 5) * 16384 + lane * 8;
      const f16* Bn = W1 + (size_t)((1024 + jb) >> 5) * 16384 + lane * 8;
#pragma unroll 2
      for (int kt = 0; kt < 32; ++kt) {
        const int koff = ((kt << 5) | klo) ^ patA;
        f16x8 a0 = *(const f16x8*)((const char*)h1s + rbase0 + koff);
        f16x8 a1 = *(const f16x8*)((const char*)h1s + rbase1 + koff);
        f16x8 br = *(const f16x8*)(Br + kt * 512);
        f16x8 bz = *(const f16x8*)(Bz + kt * 512);
        f16x8 bn = *(const f16x8*)(Bn + kt * 512);
        aR[0] = mfma16(a0, br, aR[0]);  aR[1] = mfma16(a1, br, aR[1]);
        aZ[0] = mfma16(a0, bz, aZ[0]);  aZ[1] = mfma16(a1, bz, aZ[1]);
        aN[0] = mfma16(a0, bn, aN[0]);  aN[1] = mfma16(a1, bn, aN[1]);
      }
      // partial epilogue: finish gates in registers, defer LDS writes
      const int j = jb + colid;
      const float br_ = B1[j], bz_ = B1[512 + j], bin_ = B1[1024 + j], bhn_ = B1[1536 + j];
      const float* wr = w_ih1 + j * 3;
      const float* wz = w_ih1 + (512 + j) * 3;
      const float* wn = w_ih1 + (1024 + j) * 3;
      const float wr0 = wr[0], wr1 = wr[1], wr2 = wr[2];
      const float wz0 = wz[0], wz1 = wz[1], wz2 = wz[2];
      const float wn0 = wn[0], wn1 = wn[1], wn2 = wn[2];
      const int jx = 2 * j;
#pragma unroll
      for (int rt = 0; rt < 2; ++rt) {
#pragma unroll
        for (int q = 0; q < 16; ++q) {
          const int row = (rt << 5) + (q & 3) + ((q >> 2) << 3) + (khalf << 2);
          const float4 xv = *(const float4*)(xs + row * 4);
          float gir = fmaf(xv.x, wr0, fmaf(xv.y, wr1, xv.z * wr2));
          float giz = fmaf(xv.x, wz0, fmaf(xv.y, wz1, xv.z * wz2));
          float gin = fmaf(xv.x, wn0, fmaf(xv.y, wn1, xv.z * wn2));
          float r  = sigmoid_f(aR[rt][q] + gir + br_);
          float zt = sigmoid_f(aZ[rt][q] + giz + bz_);
          float n  = tanh_f(gin + bin_ + r * (aN[rt][q] + bhn_));
          float hold = (float)*(const f16*)((const char*)h1s + row * 1024 + (jx ^ ((row & 7) << 4)));
          float hv = (1.0f - zt) * n + zt * hold;
          hnew[(c << 5) + (rt << 4) + q] = (f16)hv;
        }
      }
    }
    __syncthreads();
#pragma unroll
    for (int c = 0; c < 2; ++c) {
      const int j2 = 2 * (jw + (c << 5) + colid);
#pragma unroll
      for (int rt = 0; rt < 2; ++rt)
#pragma unroll
        for (int q = 0; q < 16; ++q) {
          const int row = (rt << 5) + (q & 3) + ((q >> 2) << 3) + (khalf << 2);
          *(f16*)((char*)h1s + row * 1024 + (j2 ^ ((row & 7) << 4))) = hnew[(c << 5) + (rt << 4) + q];
        }
    }
    __syncthreads();

    // ========== GRU layer 2: gi2 = h1new @ Wih2^T, gh2 = h2 @ Whh2^T ==========
#pragma unroll
    for (int c = 0; c < 2; ++c) {
      const int jb = jw + (c << 5);
      f32x16 aR[2], aZ[2], aI[2], aH[2];
#pragma unroll
      for (int q = 0; q < 16; ++q) {
        aR[0][q]=0.f; aR[1][q]=0.f; aZ[0][q]=0.f; aZ[1][q]=0.f;
        aI[0][q]=0.f; aI[1][q]=0.f; aH[0][q]=0.f; aH[1][q]=0.f;
      }
      const f16* Bir = Wi2 + (size_t)((jb)        >> 5) * 16384 + lane * 8;
      const f16* Biz = Wi2 + (size_t)((512 + jb)  >> 5) * 16384 + lane * 8;
      const f16* Bin = Wi2 + (size_t)((1024 + jb) >> 5) * 16384 + lane * 8;
      const f16* Bhr = Wh2 + (size_t)((jb)        >> 5) * 16384 + lane * 8;
      const f16* Bhz = Wh2 + (size_t)((512 + jb)  >> 5) * 16384 + lane * 8;
      const f16* Bhn = Wh2 + (size_t)((1024 + jb) >> 5) * 16384 + lane * 8;
#pragma unroll 2
      for (int kt = 0; kt < 32; ++kt) {
        const int koff = ((kt << 5) | klo) ^ patA;
        f16x8 a10 = *(const f16x8*)((const char*)h1s + rbase0 + koff);
        f16x8 a11 = *(const f16x8*)((const char*)h1s + rbase1 + koff);
        f16x8 a20 = *(const f16x8*)((const char*)h2s + rbase0 + koff);
        f16x8 a21 = *(const f16x8*)((const char*)h2s + rbase1 + koff);
        f16x8 bir  = *(const f16x8*)(Bir + kt * 512);
        f16x8 biz  = *(const f16x8*)(Biz + kt * 512);
        f16x8 bin8 = *(const f16x8*)(Bin + kt * 512);
        f16x8 bhr  = *(const f16x8*)(Bhr + kt * 512);
        f16x8 bhz  = *(const f16x8*)(Bhz + kt * 512);
        f16x8 bhn8 = *(const f16x8*)(Bhn + kt * 512);
        aR[0] = mfma16(a10, bir, aR[0]);  aR[0] = mfma16(a20, bhr, aR[0]);
        aR[1] = mfma16(a11, bir, aR[1]);  aR[1] = mfma16(a21, bhr, aR[1]);
        aZ[0] = mfma16(a10, biz, aZ[0]);  aZ[0] = mfma16(a20, bhz, aZ[0]);
        aZ[1] = mfma16(a11, biz, aZ[1]);  aZ[1] = mfma16(a21, bhz, aZ[1]);
        aI[0] = mfma16(a10, bin8, aI[0]); aI[1] = mfma16(a11, bin8, aI[1]);
        aH[0] = mfma16(a20, bhn8, aH[0]); aH[1] = mfma16(a21, bhn8, aH[1]);
      }
      const int j = jb + colid;
      const float br_ = B2[j], bz_ = B2[512 + j], bin_ = B2[1024 + j], bhn_ = B2[1536 + j];
      const int jx = 2 * j;
#pragma unroll
      for (int rt = 0; rt < 2; ++rt)
#pragma unroll
        for (int q = 0; q < 16; ++q) {
          const int row = (rt << 5) + (q & 3) + ((q >> 2) << 3) + (khalf << 2);
          float r  = sigmoid_f(aR[rt][q] + br_);
          float zt = sigmoid_f(aZ[rt][q] + bz_);
          float n  = tanh_f(aI[rt][q] + bin_ + r * (aH[rt][q] + bhn_));
          float hold = (float)*(const f16*)((const char*)h2s + row * 1024 + (jx ^ ((row & 7) << 4)));
          float hv = (1.0f - zt) * n + zt * hold;
          hnew[(c << 5) + (rt << 4) + q] = (f16)hv;
        }
    }
    __syncthreads();
#pragma unroll
    for (int c = 0; c < 2; ++c) {
      const int j2 = 2 * (jw + (c << 5) + colid);
#pragma unroll
      for (int rt = 0; rt < 2; ++rt)
#pragma unroll
        for (int q = 0; q < 16; ++q) {
          const int row = (rt << 5) + (q & 3) + ((q >> 2) << 3) + (khalf << 2);
          *(f16*)((char*)h2s + row * 1024 + (j2 ^ ((row & 7) << 4))) = hnew[(c << 5) + (rt << 4) + q];
        }
    }
    __syncthreads();

    // ================= FC head + x update + output =================
    if (tid < BT * 3) {
      const int rr = tid / 3, oo = tid - rr * 3;
      const float* fw = fc_w + oo * HID;
      const char* hb = (const char*)h2s + rr * 1024;
      const int pat = (rr & 7) << 4;
      float acc = 0.f;
#pragma unroll 4
      for (int kt = 0; kt < 64; ++kt) {
        f16x8 hv = *(const f16x8*)(hb + ((kt << 4) ^ pat));
        const float4 f0 = *(const float4*)(fw + (kt << 3));
        const float4 f1 = *(const float4*)(fw + (kt << 3) + 4);
        acc += (float)hv[0] * f0.x + (float)hv[1] * f0.y + (float)hv[2] * f0.z + (float)hv[3] * f0.w
             + (float)hv[4] * f1.x + (float)hv[5] * f1.y + (float)hv[6] * f1.z + (float)hv[7] * f1.w;
      }
      float xv = xs[rr * 4 + oo] + 0.1f * tanh_f(acc + fc_b[oo]);
      xs[rr * 4 + oo] = xv;
      out[(size_t)(b0 + rr) * 300 + (size_t)t * 3 + oo] = xv;
    }
    __syncthreads();
  }
}

extern "C" void kernel_launch(void* const* d_in, const int* in_sizes, int n_in,
                              void* d_out, int out_size, void* d_ws, size_t ws_size,
                              hipStream_t stream) {
  const float* z     = (const float*)d_in[0];
  const float* w_ih1 = (const float*)d_in[1];
  const float* w_hh1 = (const float*)d_in[2];
  const float* b_ih1 = (const float*)d_in[3];
  const float* b_hh1 = (const float*)d_in[4];
  const float* w_ih2 = (const float*)d_in[5];
  const float* w_hh2 = (const float*)d_in[6];
  const float* b_ih2 = (const float*)d_in[7];
  const float* b_hh2 = (const float*)d_in[8];
  const float* fc_w  = (const float*)d_in[9];
  const float* fc_b  = (const float*)d_in[10];
  float* out = (float*)d_out;

  f16*   Wp = (f16*)d_ws;                                    // 3 * 1.5 MB packed fp16
  float* Bb = (float*)((char*)d_ws + (size_t)3 * WMAT * 2);  // 2 * 8 KB combined biases

  const int nbatch = in_sizes[0] / 6;

  pack_weights<<<384, 256, 0, stream>>>(w_hh1, Wp);
  pack_weights<<<384, 256, 0, stream>>>(w_ih2, Wp + WMAT);
  pack_weights<<<384, 256, 0, stream>>>(w_hh2, Wp + 2 * WMAT);
  pack_bias<<<8, 256, 0, stream>>>(b_ih1, b_hh1, Bb);
  pack_bias<<<8, 256, 0, stream>>>(b_ih2, b_hh2, Bb + 2048);

  gru_fused<<<nbatch / BT, 512, 0, stream>>>(z, w_ih1, fc_w, fc_b, Wp, Bb, out);
}

// Round 2
// 20795.174 us; speedup vs baseline: 1.2970x; 1.2970x over previous
//
#include <hip/hip_runtime.h>

typedef _Float16 f16;
typedef _Float16 f16x8 __attribute__((ext_vector_type(8)));
typedef float f32x16 __attribute__((ext_vector_type(16)));

#define HID   512
#define BT    64
#define NSTEP 100
#define WMAT  786432   // halfs per packed weight matrix (1536*512)

__device__ __forceinline__ float sigmoid_f(float x) {
  return 1.0f / (1.0f + __expf(-x));
}
__device__ __forceinline__ float tanh_f(float x) {
  float e = __expf(2.0f * x);
  return 1.0f - 2.0f / (e + 1.0f);
}
__device__ __forceinline__ f32x16 mfma16(f16x8 a, f16x8 b, f32x16 c) {
  return __builtin_amdgcn_mfma_f32_32x32x16_f16(a, b, c, 0, 0, 0);
}
__device__ __forceinline__ f32x16 zero16() {
  f32x16 z;
#pragma unroll
  for (int i = 0; i < 16; ++i) z[i] = 0.f;
  return z;
}

// ---- weight pack: fp32 [1536][512] row-major -> B-fragment-packed fp16 ----
// layout [ct(48)][kt(32)][lane(64)][i(8)]:
//   gate = ct*32 + (lane&31), k = kt*16 + (lane>>5)*8 + i
__global__ void pack_weights(const float* __restrict__ W, f16* __restrict__ out) {
  int t = blockIdx.x * 256 + threadIdx.x;
  if (t >= 48 * 32 * 64) return;
  int lane = t & 63;
  int kt   = (t >> 6) & 31;
  int ct   = t >> 11;
  int gate = ct * 32 + (lane & 31);
  int k0   = kt * 16 + (lane >> 5) * 8;
  const float* src = W + gate * HID + k0;
  f16x8 v;
#pragma unroll
  for (int i = 0; i < 8; ++i) v[i] = (f16)src[i];
  *(f16x8*)(out + (size_t)t * 8) = v;
}

// w_ih1 [1536][3] -> B-fragments padded to K=16 (zeros for k>=3); 48 tiles x 512 halfs
__global__ void pack_wih1(const float* __restrict__ W, f16* __restrict__ out) {
  int t = blockIdx.x * 256 + threadIdx.x;
  if (t >= 48 * 64) return;
  int lane = t & 63;
  int ct   = t >> 6;
  int gate = ct * 32 + (lane & 31);
  int k0   = (lane >> 5) * 8;
  f16x8 v;
#pragma unroll
  for (int i = 0; i < 8; ++i) {
    int k = k0 + i;
    v[i] = (k < 3) ? (f16)W[gate * 3 + k] : (f16)0;
  }
  *(f16x8*)(out + (size_t)t * 8) = v;
}

// combined biases: [0..1023]=bi+bh (r,z), [1024..1535]=bi_n, [1536..2047]=bh_n
__global__ void pack_bias(const float* __restrict__ bi, const float* __restrict__ bh,
                          float* __restrict__ out) {
  int j = blockIdx.x * 256 + threadIdx.x;
  if (j < 1024)      out[j] = bi[j] + bh[j];
  else if (j < 1536) out[j] = bi[j];
  else if (j < 2048) out[j] = bh[j - 512];
}

// Persistent per-block GRU: block = 64 batch rows, 8 waves, 99 steps.
// h element (row,k) at LDS byte: row*1024 + ((2k) ^ ((row&7)<<4))
__global__ __launch_bounds__(512, 2) void gru_fused(
    const float* __restrict__ z,
    const float* __restrict__ fc_w,    // [3][512]  fp32
    const float* __restrict__ fc_b,    // [3]
    const f16*  __restrict__ Wp,       // packed Whh1 | Wih2 | Whh2
    const f16*  __restrict__ Wx,       // packed w_ih1 (K=16 padded)
    const float* __restrict__ Bb,      // bias1[2048] | bias2[2048]
    float* __restrict__ out)           // [B][100][3] fp32
{
  __shared__ f16   h1s[BT * HID];       // 64 KB
  __shared__ f16   h2s[BT * HID];       // 64 KB
  __shared__ f16   xs16[BT * 16];       // 2 KB  (x as MFMA A-tile, K=16 zero-padded)
  __shared__ float fcw[HID * 4];        // 8 KB  (fc_w transposed [k][oo])
  __shared__ float part[8 * BT * 4];    // 8 KB  (FC partial sums)

  const int tid  = threadIdx.x;
  const int lane = tid & 63;
  const int wv   = tid >> 6;
  const int b0   = blockIdx.x * BT;

  {
    f16x8 z8 = {0, 0, 0, 0, 0, 0, 0, 0};
    for (int i = tid; i < BT * HID / 8; i += 512) {
      ((f16x8*)h1s)[i] = z8;
      ((f16x8*)h2s)[i] = z8;
    }
    if (tid < BT * 2) ((f16x8*)xs16)[tid] = z8;
    if (tid < HID) {
      fcw[tid * 4 + 0] = fc_w[tid];
      fcw[tid * 4 + 1] = fc_w[HID + tid];
      fcw[tid * 4 + 2] = fc_w[2 * HID + tid];
      fcw[tid * 4 + 3] = 0.f;
    }
  }
  __syncthreads();

  int rr_ = 0, oo_ = 0;
  float xcar = 0.f, fb = 0.f;
  if (tid < BT * 3) {
    rr_ = tid / 3;
    oo_ = tid - rr_ * 3;
    xcar = z[(size_t)(b0 + rr_) * 6 + 3 + oo_];
    fb   = fc_b[oo_];
    out[(size_t)(b0 + rr_) * 300 + oo_] = xcar;     // t = 0 output
    xs16[rr_ * 16 + oo_] = (f16)xcar;
  }
  __syncthreads();

  const int colid = lane & 31;
  const int khalf = lane >> 5;
  const int klo   = khalf << 4;
  const int patA  = (colid & 7) << 4;
  const int rbase0 = colid * 1024;
  const int rbase1 = (32 + colid) * 1024;
  const int jw = wv << 6;

  const f16* W1  = Wp;
  const f16* Wi2 = Wp + WMAT;
  const f16* Wh2 = Wp + 2 * WMAT;

  // bias registers (constant over t)
  float bR1[2], bZ1[2], bN1i[2], bN1h[2], bR2[2], bZ2[2], bN2i[2], bN2h[2];
#pragma unroll
  for (int c = 0; c < 2; ++c) {
    const int j = jw + (c << 5) + colid;
    bR1[c] = Bb[j];        bZ1[c] = Bb[512 + j];
    bN1i[c] = Bb[1024 + j]; bN1h[c] = Bb[1536 + j];
    bR2[c] = Bb[2048 + j];        bZ2[c] = Bb[2048 + 512 + j];
    bN2i[c] = Bb[2048 + 1024 + j]; bN2h[c] = Bb[2048 + 1536 + j];
  }

  // register-carried h (this wave's own output elements), packed f16x8
  f16x8 hp1[8], hp2[8];
#pragma unroll
  for (int i = 0; i < 8; ++i) { hp1[i] = (f16x8){0,0,0,0,0,0,0,0}; hp2[i] = hp1[i]; }

  const int xoff0 = colid * 32 + klo;        // xs16 byte offset, rows 0..31
  const int xoff1 = (32 + colid) * 32 + klo; // rows 32..63

  for (int t = 1; t < NSTEP; ++t) {
    // ================= GRU layer 1 =================
#pragma unroll
    for (int c = 0; c < 2; ++c) {
      const int jb = jw + (c << 5);
      f32x16 aR[2], aZ[2], aN[2], aNx[2];
      {
        f16x8 ax0 = *(const f16x8*)((const char*)xs16 + xoff0);
        f16x8 ax1 = *(const f16x8*)((const char*)xs16 + xoff1);
        f16x8 br = *(const f16x8*)(Wx + (size_t)((jb) >> 5) * 512 + lane * 8);
        f16x8 bz = *(const f16x8*)(Wx + (size_t)((512 + jb) >> 5) * 512 + lane * 8);
        f16x8 bn = *(const f16x8*)(Wx + (size_t)((1024 + jb) >> 5) * 512 + lane * 8);
        f32x16 zz = zero16();
        aR[0] = mfma16(ax0, br, zz);  aR[1] = mfma16(ax1, br, zz);
        aZ[0] = mfma16(ax0, bz, zz);  aZ[1] = mfma16(ax1, bz, zz);
        aNx[0] = mfma16(ax0, bn, zz); aNx[1] = mfma16(ax1, bn, zz);
        aN[0] = zz; aN[1] = zz;
      }
      const f16* Br = W1 + (size_t)((jb) >> 5) * 16384 + lane * 8;
      const f16* Bz = W1 + (size_t)((512 + jb) >> 5) * 16384 + lane * 8;
      const f16* Bn = W1 + (size_t)((1024 + jb) >> 5) * 16384 + lane * 8;
#pragma unroll 2
      for (int kt = 0; kt < 32; ++kt) {
        const int koff = ((kt << 5) | klo) ^ patA;
        f16x8 a0 = *(const f16x8*)((const char*)h1s + rbase0 + koff);
        f16x8 a1 = *(const f16x8*)((const char*)h1s + rbase1 + koff);
        f16x8 br = *(const f16x8*)(Br + kt * 512);
        f16x8 bz = *(const f16x8*)(Bz + kt * 512);
        f16x8 bn = *(const f16x8*)(Bn + kt * 512);
        aR[0] = mfma16(a0, br, aR[0]);  aR[1] = mfma16(a1, br, aR[1]);
        aZ[0] = mfma16(a0, bz, aZ[0]);  aZ[1] = mfma16(a1, bz, aZ[1]);
        aN[0] = mfma16(a0, bn, aN[0]);  aN[1] = mfma16(a1, bn, aN[1]);
      }
#pragma unroll
      for (int rt = 0; rt < 2; ++rt)
#pragma unroll
        for (int q = 0; q < 16; ++q) {
          const int idx = (c << 5) + (rt << 4) + q;
          float r  = sigmoid_f(aR[rt][q] + bR1[c]);
          float zt = sigmoid_f(aZ[rt][q] + bZ1[c]);
          float n  = tanh_f(aNx[rt][q] + bN1i[c] + r * (aN[rt][q] + bN1h[c]));
          float hold = (float)hp1[idx >> 3][idx & 7];
          hp1[idx >> 3][idx & 7] = (f16)((1.0f - zt) * n + zt * hold);
        }
    }
    __syncthreads();
#pragma unroll
    for (int c = 0; c < 2; ++c) {
      const int j2 = 2 * (jw + (c << 5) + colid);
#pragma unroll
      for (int rt = 0; rt < 2; ++rt)
#pragma unroll
        for (int q = 0; q < 16; ++q) {
          const int idx = (c << 5) + (rt << 4) + q;
          const int row = (rt << 5) + (q & 3) + ((q >> 2) << 3) + (khalf << 2);
          *(f16*)((char*)h1s + row * 1024 + (j2 ^ ((row & 7) << 4))) = hp1[idx >> 3][idx & 7];
        }
    }
    __syncthreads();

    // ================= GRU layer 2 =================
#pragma unroll
    for (int c = 0; c < 2; ++c) {
      const int jb = jw + (c << 5);
      f32x16 aR[2], aZ[2], aI[2], aH[2];
      {
        f32x16 zz = zero16();
        aR[0] = zz; aR[1] = zz; aZ[0] = zz; aZ[1] = zz;
        aI[0] = zz; aI[1] = zz; aH[0] = zz; aH[1] = zz;
      }
      const f16* Bir = Wi2 + (size_t)((jb) >> 5) * 16384 + lane * 8;
      const f16* Biz = Wi2 + (size_t)((512 + jb) >> 5) * 16384 + lane * 8;
      const f16* Bin = Wi2 + (size_t)((1024 + jb) >> 5) * 16384 + lane * 8;
      const f16* Bhr = Wh2 + (size_t)((jb) >> 5) * 16384 + lane * 8;
      const f16* Bhz = Wh2 + (size_t)((512 + jb) >> 5) * 16384 + lane * 8;
      const f16* Bhn = Wh2 + (size_t)((1024 + jb) >> 5) * 16384 + lane * 8;
#pragma unroll 2
      for (int kt = 0; kt < 32; ++kt) {
        const int koff = ((kt << 5) | klo) ^ patA;
        f16x8 a10 = *(const f16x8*)((const char*)h1s + rbase0 + koff);
        f16x8 a11 = *(const f16x8*)((const char*)h1s + rbase1 + koff);
        f16x8 a20 = *(const f16x8*)((const char*)h2s + rbase0 + koff);
        f16x8 a21 = *(const f16x8*)((const char*)h2s + rbase1 + koff);
        f16x8 bir  = *(const f16x8*)(Bir + kt * 512);
        f16x8 biz  = *(const f16x8*)(Biz + kt * 512);
        f16x8 bin8 = *(const f16x8*)(Bin + kt * 512);
        f16x8 bhr  = *(const f16x8*)(Bhr + kt * 512);
        f16x8 bhz  = *(const f16x8*)(Bhz + kt * 512);
        f16x8 bhn8 = *(const f16x8*)(Bhn + kt * 512);
        aR[0] = mfma16(a10, bir, aR[0]);  aR[0] = mfma16(a20, bhr, aR[0]);
        aR[1] = mfma16(a11, bir, aR[1]);  aR[1] = mfma16(a21, bhr, aR[1]);
        aZ[0] = mfma16(a10, biz, aZ[0]);  aZ[0] = mfma16(a20, bhz, aZ[0]);
        aZ[1] = mfma16(a11, biz, aZ[1]);  aZ[1] = mfma16(a21, bhz, aZ[1]);
        aI[0] = mfma16(a10, bin8, aI[0]); aI[1] = mfma16(a11, bin8, aI[1]);
        aH[0] = mfma16(a20, bhn8, aH[0]); aH[1] = mfma16(a21, bhn8, aH[1]);
      }
#pragma unroll
      for (int rt = 0; rt < 2; ++rt)
#pragma unroll
        for (int q = 0; q < 16; ++q) {
          const int idx = (c << 5) + (rt << 4) + q;
          float r  = sigmoid_f(aR[rt][q] + bR2[c]);
          float zt = sigmoid_f(aZ[rt][q] + bZ2[c]);
          float n  = tanh_f(aI[rt][q] + bN2i[c] + r * (aH[rt][q] + bN2h[c]));
          float hold = (float)hp2[idx >> 3][idx & 7];
          hp2[idx >> 3][idx & 7] = (f16)((1.0f - zt) * n + zt * hold);
        }
    }
    __syncthreads();
#pragma unroll
    for (int c = 0; c < 2; ++c) {
      const int j2 = 2 * (jw + (c << 5) + colid);
#pragma unroll
      for (int rt = 0; rt < 2; ++rt)
#pragma unroll
        for (int q = 0; q < 16; ++q) {
          const int idx = (c << 5) + (rt << 4) + q;
          const int row = (rt << 5) + (q & 3) + ((q >> 2) << 3) + (khalf << 2);
          *(f16*)((char*)h2s + row * 1024 + (j2 ^ ((row & 7) << 4))) = hp2[idx >> 3][idx & 7];
        }
    }
    __syncthreads();

    // ================= FC head (all 512 threads) =================
    {
      const int r = lane;
      const int s = wv;
      const char* hb = (const char*)h2s + r * 1024;
      const int pat = (r & 7) << 4;
      float p0 = 0.f, p1 = 0.f, p2 = 0.f;
#pragma unroll
      for (int k8 = 0; k8 < 8; ++k8) {
        const int kt = (s << 3) + k8;
        f16x8 hv = *(const f16x8*)(hb + ((kt << 4) ^ pat));
#pragma unroll
        for (int i = 0; i < 8; ++i) {
          const float hf = (float)hv[i];
          const float4 fw4 = *(const float4*)(fcw + ((kt << 3) + i) * 4);
          p0 = fmaf(hf, fw4.x, p0);
          p1 = fmaf(hf, fw4.y, p1);
          p2 = fmaf(hf, fw4.z, p2);
        }
      }
      float* pp = part + ((s << 6) + r) * 4;
      pp[0] = p0; pp[1] = p1; pp[2] = p2;
    }
    __syncthreads();
    if (tid < BT * 3) {
      float acc = fb;
#pragma unroll
      for (int s = 0; s < 8; ++s) acc += part[((s << 6) + rr_) * 4 + oo_];
      float xv = xcar + 0.1f * tanh_f(acc);
      xcar = xv;
      xs16[rr_ * 16 + oo_] = (f16)xv;
      out[(size_t)(b0 + rr_) * 300 + (size_t)t * 3 + oo_] = xv;
    }
    __syncthreads();
  }
}

extern "C" void kernel_launch(void* const* d_in, const int* in_sizes, int n_in,
                              void* d_out, int out_size, void* d_ws, size_t ws_size,
                              hipStream_t stream) {
  const float* z     = (const float*)d_in[0];
  const float* w_ih1 = (const float*)d_in[1];
  const float* w_hh1 = (const float*)d_in[2];
  const float* b_ih1 = (const float*)d_in[3];
  const float* b_hh1 = (const float*)d_in[4];
  const float* w_ih2 = (const float*)d_in[5];
  const float* w_hh2 = (const float*)d_in[6];
  const float* b_ih2 = (const float*)d_in[7];
  const float* b_hh2 = (const float*)d_in[8];
  const float* fc_w  = (const float*)d_in[9];
  const float* fc_b  = (const float*)d_in[10];
  float* out = (float*)d_out;

  f16*   Wp = (f16*)d_ws;                                          // 3 * 1.5 MB packed fp16
  f16*   Wx = (f16*)((char*)d_ws + (size_t)3 * WMAT * 2);          // 48 KB packed w_ih1
  float* Bb = (float*)((char*)d_ws + (size_t)3 * WMAT * 2 + 48 * 512 * 2);

  const int nbatch = in_sizes[0] / 6;

  pack_weights<<<384, 256, 0, stream>>>(w_hh1, Wp);
  pack_weights<<<384, 256, 0, stream>>>(w_ih2, Wp + WMAT);
  pack_weights<<<384, 256, 0, stream>>>(w_hh2, Wp + 2 * WMAT);
  pack_wih1<<<12, 256, 0, stream>>>(w_ih1, Wx);
  pack_bias<<<8, 256, 0, stream>>>(b_ih1, b_hh1, Bb);
  pack_bias<<<8, 256, 0, stream>>>(b_ih2, b_hh2, Bb + 2048);

  gru_fused<<<nbatch / BT, 512, 0, stream>>>(z, fc_w, fc_b, Wp, Wx, Bb, out);
}